// Round 1
// baseline (18368.347 us; speedup 1.0000x reference)
//
#include <hip/hip_runtime.h>

#define BB 512
#define TT 128
#define EE 512
#define HH 256
#define VV 39
#define H3 768
#define H2 512
#define TM1 127
#define NEGF (-3.402823466e38f)

typedef unsigned short u16;
typedef unsigned int u32;

__device__ __forceinline__ float b2f(u16 u){ u32 x=((u32)u)<<16; return __uint_as_float(x); }
__device__ __forceinline__ u16 f2b(float f){ u32 x=__float_as_uint(f); u32 r=(x+0x7fffu+((x>>16)&1u))>>16; return (u16)r; }
__device__ __forceinline__ float sigm(float x){ return 1.f/(1.f+__expf(-x)); }
__device__ __forceinline__ float tanh1(float x){ float t=__expf(2.f*x); return 1.f-2.f/(t+1.f); }

// ---------------------------------------------------------------------------
// Build per-token input-projection tables (V=39 rows):
//   tab_gi_f[v][n] = src_emb[v] . Wih_f[n] + bih_f[n]      (n<768)
//   tab_gi_b likewise, tab_dec[v][n] = trg_emb[v] . dec_Wih[n][0:512] + dec_bih[n]
//   tab_pre[v][n] = trg_emb[v] . pre_W[n][0:512]           (n<256)
// grid (39, 10), block 256
__global__ __launch_bounds__(256) void k_tables(
    const float* __restrict__ src_emb, const float* __restrict__ trg_emb,
    const float* __restrict__ Wih_f, const float* __restrict__ bih_f,
    const float* __restrict__ Wih_b, const float* __restrict__ bih_b,
    const float* __restrict__ dec_Wih, const float* __restrict__ dec_bih,
    const float* __restrict__ pre_W,
    float* __restrict__ tab_gi_f, float* __restrict__ tab_gi_b,
    float* __restrict__ tab_dec, float* __restrict__ tab_pre)
{
  int v = blockIdx.x;
  int y = blockIdx.y;
  int tid = threadIdx.x;
  if (y < 9){
    int seg = y/3, part = y%3;
    int n = part*256 + tid;
    const float* emb; const float* W; const float* bias; float* out; int ldw;
    if (seg==0){ emb=src_emb; W=Wih_f; bias=bih_f; out=tab_gi_f; ldw=EE; }
    else if (seg==1){ emb=src_emb; W=Wih_b; bias=bih_b; out=tab_gi_b; ldw=EE; }
    else { emb=trg_emb; W=dec_Wih; bias=dec_bih; out=tab_dec; ldw=EE+H2; }
    float acc = bias[n];
    const float* er = emb + (size_t)v*EE;
    const float* wr = W + (size_t)n*ldw;
    for (int k=0;k<EE;k++) acc += er[k]*wr[k];
    out[(size_t)v*H3 + n] = acc;
  } else {
    int n = tid;
    float acc = 0.f;
    const float* er = trg_emb + (size_t)v*EE;
    const float* wr = pre_W + (size_t)n*1280;
    for (int k=0;k<EE;k++) acc += er[k]*wr[k];
    tab_pre[(size_t)v*HH + n] = acc;
  }
}

// ---------------------------------------------------------------------------
// Encoder step s (s=0..127). One kernel does BOTH directions.
// Phase A: recompute gates of step s-1 -> h_state_s rows for this block's
//          m-tile into LDS (bf16). Designated blocks persist h and enc_out.
// Phase B: gh_s = h_state_s @ Whh^T  (M=512 x N=768 per dir, K=256)
// grid (24, 8): x = n-tile (0..11 fwd, 12..23 bwd), y = m-tile. block 256.
__global__ __launch_bounds__(256) void k_enc_step(int s, const int* __restrict__ input,
    const float* __restrict__ Whh_f, const float* __restrict__ Whh_b,
    const float* __restrict__ bhh_f, const float* __restrict__ bhh_b,
    const float* __restrict__ tab_f, const float* __restrict__ tab_b,
    float* __restrict__ h_f, float* __restrict__ h_b,
    float* __restrict__ gh_enc, u16* __restrict__ enc_out)
{
  __shared__ u16  As[256][68];   // As[k][row] = h_state_s[m0+row][k] (bf16)
  __shared__ float Ws[32][68];   // Ws[k][w]  = Whh[n0+w][ko+k]
  int xt = blockIdx.x;
  int dirb = (xt>=12)?1:0;
  int nt = xt - dirb*12;
  int m0 = blockIdx.y*64, n0 = nt*64;
  int tid = threadIdx.x;
  float* ghW = gh_enc + (size_t)(s&1)*BB*1536 + dirb*H3;
  if (s == 0){
    // h_state_0 = 0  ->  gh_0 = 0
    for (int it=0;it<16;it++){
      int e = it*256 + tid; int r = e>>6, cc = e&63;
      ghW[(size_t)(m0+r)*1536 + n0 + cc] = 0.f;
    }
    return;
  }
  const float* tab = dirb ? tab_b : tab_f;
  const float* Whh = dirb ? Whh_b : Whh_f;
  const float* bhh = dirb ? bhh_b : bhh_f;
  float* hW = (dirb? h_b : h_f) + (size_t)(s&1)*BB*HH;
  const float* hR = (dirb? h_b : h_f) + (size_t)((s-1)&1)*BB*HH;
  const float* ghR = gh_enc + (size_t)((s-1)&1)*BB*1536 + dirb*H3;
  int tcol = dirb ? (TT - s) : (s - 1);
  int c = tid;
  float b_r = bhh[c], b_z = bhh[c+256], b_n = bhh[c+512];
  bool desig = (nt==0);
  for (int r=0;r<64;r++){
    int b = m0 + r;
    int tok = input[b*TT + tcol];
    const float* tg = tab + (size_t)tok*H3;
    const float* gr = ghR + (size_t)b*1536;
    float hp = (s==1) ? 0.f : hR[b*HH + c];
    float rg = sigm(tg[c]     + gr[c]     + b_r);
    float zg = sigm(tg[c+256] + gr[c+256] + b_z);
    float ng = tanh1(tg[c+512] + rg*(gr[c+512] + b_n));
    float hv = (1.f - zg)*ng + zg*hp;
    As[c][r] = f2b(hv);
    if (desig){
      hW[b*HH + c] = hv;
      enc_out[((size_t)b*TT + tcol)*H2 + dirb*HH + c] = f2b(hv);
    }
  }
  __syncthreads();
  int rt = tid>>4, ct = tid&15;
  int wr = tid>>2, wk = (tid&3)*8;
  float acc[4][4];
  #pragma unroll
  for (int j=0;j<4;j++){
    #pragma unroll
    for (int l=0;l<4;l++) acc[j][l]=0.f;
  }
  for (int ko=0;ko<256;ko+=32){
    const float* wsrc = Whh + (size_t)(n0+wr)*HH + ko + wk;
    float4 w0 = *(const float4*)wsrc;
    float4 w1 = *(const float4*)(wsrc+4);
    __syncthreads();
    Ws[wk+0][wr]=w0.x; Ws[wk+1][wr]=w0.y; Ws[wk+2][wr]=w0.z; Ws[wk+3][wr]=w0.w;
    Ws[wk+4][wr]=w1.x; Ws[wk+5][wr]=w1.y; Ws[wk+6][wr]=w1.z; Ws[wk+7][wr]=w1.w;
    __syncthreads();
    #pragma unroll
    for (int kk=0;kk<32;kk++){
      ushort4 av = *(const ushort4*)&As[ko+kk][rt*4];
      float4  wv = *(const float4*)&Ws[kk][ct*4];
      float a4[4] = {b2f(av.x),b2f(av.y),b2f(av.z),b2f(av.w)};
      float w4[4] = {wv.x,wv.y,wv.z,wv.w};
      #pragma unroll
      for (int j=0;j<4;j++){
        #pragma unroll
        for (int l=0;l<4;l++) acc[j][l] += a4[j]*w4[l];
      }
    }
  }
  #pragma unroll
  for (int j=0;j<4;j++){
    float4 ov; ov.x=acc[j][0]; ov.y=acc[j][1]; ov.z=acc[j][2]; ov.w=acc[j][3];
    *(float4*)&ghW[(size_t)(m0+rt*4+j)*1536 + n0 + ct*4] = ov;
  }
}

// Encoder tail (s=128): gates only, both dirs. grid (2,8), block 256.
__global__ __launch_bounds__(256) void k_enc_final(const int* __restrict__ input,
    const float* __restrict__ bhh_f, const float* __restrict__ bhh_b,
    const float* __restrict__ tab_f, const float* __restrict__ tab_b,
    float* __restrict__ h_f, float* __restrict__ h_b,
    const float* __restrict__ gh_enc, u16* __restrict__ enc_out)
{
  int dirb = blockIdx.x;
  int m0 = blockIdx.y*64;
  int c = threadIdx.x;
  const float* tab = dirb? tab_b : tab_f;
  const float* bhh = dirb? bhh_b : bhh_f;
  float* hW = (dirb? h_b : h_f);                       // parity 0 (s=128)
  const float* hR = (dirb? h_b : h_f) + (size_t)BB*HH; // parity 1
  const float* ghR = gh_enc + (size_t)BB*1536 + dirb*H3; // parity 1
  int tcol = dirb ? 0 : 127;
  float b_r=bhh[c], b_z=bhh[c+256], b_n=bhh[c+512];
  for (int r=0;r<64;r++){
    int b=m0+r;
    int tok=input[b*TT+tcol];
    const float* tg = tab + (size_t)tok*H3;
    const float* gr = ghR + (size_t)b*1536;
    float rg=sigm(tg[c]+gr[c]+b_r);
    float zg=sigm(tg[c+256]+gr[c+256]+b_z);
    float ng=tanh1(tg[c+512]+rg*(gr[c+512]+b_n));
    float hv=(1.f-zg)*ng+zg*hR[b*HH+c];
    hW[b*HH+c]=hv;
    enc_out[((size_t)b*TT+tcol)*H2 + dirb*HH + c]=f2b(hv);
  }
}

// proj_key = enc_out @ attn_Wk^T : M=65536, N=256, K=512. grid (4, 1024).
__global__ __launch_bounds__(256) void k_pk(const u16* __restrict__ enc_out,
    const float* __restrict__ Wk, u16* __restrict__ pk)
{
  __shared__ float As[32][68];
  __shared__ float Ws[32][68];
  int n0=blockIdx.x*64, m0=blockIdx.y*64, tid=threadIdx.x;
  int ar=tid>>2, ak=(tid&3)*8;
  int rt=tid>>4, ct=tid&15;
  float acc[4][4];
  #pragma unroll
  for (int j=0;j<4;j++){
    #pragma unroll
    for (int l=0;l<4;l++) acc[j][l]=0.f;
  }
  for (int ko=0;ko<512;ko+=32){
    const u16* asrc = enc_out + (size_t)(m0+ar)*H2 + ko+ak;
    ushort4 a0 = *(const ushort4*)asrc;
    ushort4 a1 = *(const ushort4*)(asrc+4);
    const float* wsrc = Wk + (size_t)(n0+ar)*H2 + ko+ak;
    float4 w0=*(const float4*)wsrc, w1=*(const float4*)(wsrc+4);
    __syncthreads();
    As[ak+0][ar]=b2f(a0.x); As[ak+1][ar]=b2f(a0.y); As[ak+2][ar]=b2f(a0.z); As[ak+3][ar]=b2f(a0.w);
    As[ak+4][ar]=b2f(a1.x); As[ak+5][ar]=b2f(a1.y); As[ak+6][ar]=b2f(a1.z); As[ak+7][ar]=b2f(a1.w);
    Ws[ak+0][ar]=w0.x; Ws[ak+1][ar]=w0.y; Ws[ak+2][ar]=w0.z; Ws[ak+3][ar]=w0.w;
    Ws[ak+4][ar]=w1.x; Ws[ak+5][ar]=w1.y; Ws[ak+6][ar]=w1.z; Ws[ak+7][ar]=w1.w;
    __syncthreads();
    #pragma unroll
    for (int kk=0;kk<32;kk++){
      float4 a=*(const float4*)&As[kk][rt*4];
      float4 w=*(const float4*)&Ws[kk][ct*4];
      float a4[4]={a.x,a.y,a.z,a.w};
      float w4[4]={w.x,w.y,w.z,w.w};
      #pragma unroll
      for (int j=0;j<4;j++){
        #pragma unroll
        for (int l=0;l<4;l++) acc[j][l]+=a4[j]*w4[l];
      }
    }
  }
  #pragma unroll
  for (int j=0;j<4;j++){
    ushort4 ov;
    ov.x=f2b(acc[j][0]); ov.y=f2b(acc[j][1]); ov.z=f2b(acc[j][2]); ov.w=f2b(acc[j][3]);
    *(ushort4*)&pk[(size_t)(m0+rt*4+j)*HH + n0 + ct*4] = ov;
  }
}

// hidden = tanh([h_f_final|h_b_final] @ bridge_W^T + b). M=512,N=256,K=512. grid (4,8).
__global__ __launch_bounds__(256) void k_bridge(const float* __restrict__ h_f,
    const float* __restrict__ h_b, const float* __restrict__ bw,
    const float* __restrict__ bb, float* __restrict__ hd)
{
  __shared__ float As[32][68];
  __shared__ float Ws[32][68];
  int n0=blockIdx.x*64, m0=blockIdx.y*64, tid=threadIdx.x;
  int ar=tid>>2, ak=(tid&3)*8;
  int rt=tid>>4, ct=tid&15;
  float acc[4][4];
  #pragma unroll
  for (int j=0;j<4;j++){
    #pragma unroll
    for (int l=0;l<4;l++) acc[j][l]=0.f;
  }
  for (int ko=0;ko<512;ko+=32){
    int k0=ko+ak;
    const float* asrc = (k0<256)? (h_f + (size_t)(m0+ar)*HH + k0)
                                : (h_b + (size_t)(m0+ar)*HH + (k0-256));
    float4 a0=*(const float4*)asrc, a1=*(const float4*)(asrc+4);
    const float* wsrc = bw + (size_t)(n0+ar)*H2 + k0;
    float4 w0=*(const float4*)wsrc, w1=*(const float4*)(wsrc+4);
    __syncthreads();
    As[ak+0][ar]=a0.x; As[ak+1][ar]=a0.y; As[ak+2][ar]=a0.z; As[ak+3][ar]=a0.w;
    As[ak+4][ar]=a1.x; As[ak+5][ar]=a1.y; As[ak+6][ar]=a1.z; As[ak+7][ar]=a1.w;
    Ws[ak+0][ar]=w0.x; Ws[ak+1][ar]=w0.y; Ws[ak+2][ar]=w0.z; Ws[ak+3][ar]=w0.w;
    Ws[ak+4][ar]=w1.x; Ws[ak+5][ar]=w1.y; Ws[ak+6][ar]=w1.z; Ws[ak+7][ar]=w1.w;
    __syncthreads();
    #pragma unroll
    for (int kk=0;kk<32;kk++){
      float4 a=*(const float4*)&As[kk][rt*4];
      float4 w=*(const float4*)&Ws[kk][ct*4];
      float a4[4]={a.x,a.y,a.z,a.w};
      float w4[4]={w.x,w.y,w.z,w.w};
      #pragma unroll
      for (int j=0;j<4;j++){
        #pragma unroll
        for (int l=0;l<4;l++) acc[j][l]+=a4[j]*w4[l];
      }
    }
  }
  #pragma unroll
  for (int j=0;j<4;j++){
    int row=m0+rt*4+j;
    #pragma unroll
    for (int l=0;l<4;l++){
      int col=n0+ct*4+l;
      hd[(size_t)row*HH+col]=tanh1(acc[j][l]+bb[col]);
    }
  }
}

// Decoder gates (step i-1) + q_i = h^(i) @ Wq^T. Tile 32x32, K=256. grid (8,16).
__global__ __launch_bounds__(256) void k_dec_g(int i, int do_q, const int* __restrict__ input,
    const float* __restrict__ Wq, const float* __restrict__ tab_dec,
    const float* __restrict__ bhh, const float* __restrict__ gh_dec,
    const float* __restrict__ gi_dec, float* __restrict__ hd, float* __restrict__ q)
{
  __shared__ float As[256][36];   // As[k][row] = h^(i)[m0+row][k]
  __shared__ float Ws[32][36];
  int n0 = blockIdx.x*32, m0 = blockIdx.y*32;
  int tid = threadIdx.x; int c = tid;
  float* hdW = hd + (size_t)(i&1)*BB*HH;
  if (i == 0){
    const float* h0 = hd; // parity 0 = bridge output
    for (int r=0;r<32;r++) As[c][r] = h0[(size_t)(m0+r)*HH + c];
  } else {
    int p = (i-1)&1;
    const float* ghR  = gh_dec + (size_t)p*BB*H3;
    const float* giR0 = gi_dec + ((size_t)p*2 + 0)*BB*H3;
    const float* giR1 = gi_dec + ((size_t)p*2 + 1)*BB*H3;
    const float* hR   = hd + (size_t)p*BB*HH;
    float b_r=bhh[c], b_z=bhh[c+256], b_n=bhh[c+512];
    bool desig = (blockIdx.x==0);
    for (int r=0;r<32;r++){
      int b = m0+r;
      int tok = input[b*TT + (i-1)];
      const float* tg = tab_dec + (size_t)tok*H3;
      float gi_r = tg[c]     + giR0[(size_t)b*H3 + c]     + giR1[(size_t)b*H3 + c];
      float gi_z = tg[c+256] + giR0[(size_t)b*H3 + c+256] + giR1[(size_t)b*H3 + c+256];
      float gi_n = tg[c+512] + giR0[(size_t)b*H3 + c+512] + giR1[(size_t)b*H3 + c+512];
      const float* gr = ghR + (size_t)b*H3;
      float rg = sigm(gi_r + gr[c] + b_r);
      float zg = sigm(gi_z + gr[c+256] + b_z);
      float ng = tanh1(gi_n + rg*(gr[c+512] + b_n));
      float hv = (1.f-zg)*ng + zg*hR[b*HH + c];
      As[c][r] = hv;
      if (desig) hdW[b*HH + c] = hv;
    }
  }
  __syncthreads();
  if (!do_q) return;
  int rt = tid>>4, ct = tid&15;
  int wr = tid>>3, wk = (tid&7)*4;
  float a00=0.f,a01=0.f,a10=0.f,a11=0.f;
  for (int ko=0;ko<256;ko+=32){
    float4 w = *(const float4*)(Wq + (size_t)(n0+wr)*HH + ko + wk);
    __syncthreads();
    Ws[wk+0][wr]=w.x; Ws[wk+1][wr]=w.y; Ws[wk+2][wr]=w.z; Ws[wk+3][wr]=w.w;
    __syncthreads();
    #pragma unroll
    for (int kk=0;kk<32;kk++){
      float2 a = *(const float2*)&As[ko+kk][rt*2];
      float2 b = *(const float2*)&Ws[kk][ct*2];
      a00 += a.x*b.x; a01 += a.x*b.y; a10 += a.y*b.x; a11 += a.y*b.y;
    }
  }
  q[(size_t)(m0+rt*2+0)*HH + n0+ct*2+0] = a00;
  q[(size_t)(m0+rt*2+0)*HH + n0+ct*2+1] = a01;
  q[(size_t)(m0+rt*2+1)*HH + n0+ct*2+0] = a10;
  q[(size_t)(m0+rt*2+1)*HH + n0+ct*2+1] = a11;
}

// Attention for step i (+ nll for step i-2). One block per batch row. grid (512).
__global__ __launch_bounds__(256) void k_dec_attn(int i, int do_attn, const int* __restrict__ input,
    const float* __restrict__ q, const u16* __restrict__ pk, const u16* __restrict__ enc_out,
    const float* __restrict__ We, const float* __restrict__ genW,
    const float* __restrict__ tab_pre, const float* __restrict__ pre_b,
    float* __restrict__ ctx, float* __restrict__ nll)
{
  __shared__ float se[128];
  __shared__ float sa[128];
  __shared__ float spre[256];
  __shared__ int   stok[128];
  __shared__ float redm[4];
  __shared__ float reds[4];
  int b = blockIdx.x;
  int tid = threadIdx.x;
  int lane = tid & 63;
  int w = tid >> 6;
  int do_nll = (i >= 2);
  if (do_attn && tid < 128) stok[tid] = input[b*TT + tid];
  if (do_nll){
    int tokp = input[b*TT + (i-2)];
    const float* pp = pre_b + (size_t)(i&1)*3*BB*HH;  // parity (i-2)&1 == i&1
    spre[tid] = tab_pre[(size_t)tokp*HH + tid]
              + pp[(size_t)b*HH + tid]
              + pp[(size_t)BB*HH + (size_t)b*HH + tid]
              + pp[(size_t)2*BB*HH + (size_t)b*HH + tid];
  }
  __syncthreads();
  if (do_nll && w==0){
    float lg = NEGF;
    if (lane < VV){
      float s=0.f;
      const float* gw = genW + (size_t)lane*HH;
      for (int d=0; d<HH; d++) s += spre[d]*gw[d];
      lg = s;
    }
    float m = lg;
    #pragma unroll
    for (int off=32; off; off>>=1) m = fmaxf(m, __shfl_xor(m, off));
    float pe = (lane<VV)? __expf(lg - m) : 0.f;
    float ssum = pe;
    #pragma unroll
    for (int off=32; off; off>>=1) ssum += __shfl_xor(ssum, off);
    int ty = input[b*TT + (i-1)];
    float lty = __shfl(lg, ty);
    if (lane==0){
      float val = (ty != 0) ? (m + __logf(ssum) - lty) : 0.f;
      nll[(size_t)(i-2)*BB + b] = val;
    }
  }
  if (do_attn){
    // e[t] = We . tanh(q[b] + pk[b][t]); wave w handles t in [w*32, w*32+32)
    float4 qv = *(const float4*)(q + (size_t)b*HH + lane*4);
    float4 wv = *(const float4*)(We + lane*4);
    const u16* pkb = pk + (size_t)b*TT*HH;
    for (int it=0; it<32; it++){
      int t = w*32 + it;
      ushort4 kv = *(const ushort4*)(pkb + (size_t)t*HH + lane*4);
      float s = tanh1(qv.x + b2f(kv.x))*wv.x + tanh1(qv.y + b2f(kv.y))*wv.y
              + tanh1(qv.z + b2f(kv.z))*wv.z + tanh1(qv.w + b2f(kv.w))*wv.w;
      #pragma unroll
      for (int off=32; off; off>>=1) s += __shfl_xor(s, off);
      if (lane==0) se[t] = (stok[t] != 0) ? s : NEGF;
    }
    __syncthreads();
    // softmax over 128
    float v = (tid<128)? se[tid] : NEGF;
    float mm = v;
    #pragma unroll
    for (int off=32; off; off>>=1) mm = fmaxf(mm, __shfl_xor(mm, off));
    if (lane==0) redm[w]=mm;
    __syncthreads();
    float M = fmaxf(fmaxf(redm[0],redm[1]), fmaxf(redm[2],redm[3]));
    float pv = (tid<128)? __expf(v - M) : 0.f;
    float ps = pv;
    #pragma unroll
    for (int off=32; off; off>>=1) ps += __shfl_xor(ps, off);
    if (lane==0) reds[w]=ps;
    __syncthreads();
    float S = reds[0]+reds[1]+reds[2]+reds[3];
    if (tid<128) sa[tid] = pv/S;
    __syncthreads();
    // ctx[b][d] = sum_t a[t]*enc_out[b][t][d]; d = tid and tid+256
    const u16* eb = enc_out + (size_t)b*TT*H2;
    float c0=0.f, c1=0.f;
    for (int t=0;t<TT;t++){
      float a = sa[t];
      c0 += a*b2f(eb[(size_t)t*H2 + tid]);
      c1 += a*b2f(eb[(size_t)t*H2 + 256 + tid]);
    }
    float* cw = ctx + (size_t)(i&1)*BB*H2 + (size_t)b*H2;
    cw[tid] = c0;
    cw[tid+256] = c1;
  }
}

// Decoder GEMMs: gh_i, gi_i (2 K-parts), pre_{i-1} (3 K-parts). 64x64 tiles, K=256.
// grid (48 or 36 (+xoff for tail), 8), block 256.
__global__ __launch_bounds__(256) void k_dec_gemm(int i, int xoff,
    const float* __restrict__ hd, const float* __restrict__ ctx,
    const float* __restrict__ dec_Whh, const float* __restrict__ dec_Wih,
    const float* __restrict__ pre_W,
    float* __restrict__ gh_dec, float* __restrict__ gi_dec, float* __restrict__ pre_b)
{
  __shared__ float As[32][68];
  __shared__ float Ws[32][68];
  int x = blockIdx.x + xoff;
  int m0 = blockIdx.y*64;
  int tid = threadIdx.x;
  const float* hdC  = hd  + (size_t)(i&1)*BB*HH;
  const float* ctxC = ctx + (size_t)(i&1)*BB*H2;
  const float* ctxP = ctx + (size_t)((i-1)&1)*BB*H2;
  const float* aptr; int lda; const float* wptr; int ldw; float* optr; int ldo; int n0;
  if (x < 12){        n0=x*64;      aptr=hdC;      lda=HH; wptr=dec_Whh;      ldw=HH;   optr=gh_dec + (size_t)(i&1)*BB*H3;           ldo=H3; }
  else if (x < 24){   n0=(x-12)*64; aptr=ctxC;     lda=H2; wptr=dec_Wih+512;  ldw=1024; optr=gi_dec + ((size_t)(i&1)*2+0)*BB*H3;     ldo=H3; }
  else if (x < 36){   n0=(x-24)*64; aptr=ctxC+256; lda=H2; wptr=dec_Wih+768;  ldw=1024; optr=gi_dec + ((size_t)(i&1)*2+1)*BB*H3;     ldo=H3; }
  else if (x < 40){   n0=(x-36)*64; aptr=hdC;      lda=HH; wptr=pre_W+512;    ldw=1280; optr=pre_b + ((size_t)((i-1)&1)*3+0)*BB*HH;  ldo=HH; }
  else if (x < 44){   n0=(x-40)*64; aptr=ctxP;     lda=H2; wptr=pre_W+768;    ldw=1280; optr=pre_b + ((size_t)((i-1)&1)*3+1)*BB*HH;  ldo=HH; }
  else {              n0=(x-44)*64; aptr=ctxP+256; lda=H2; wptr=pre_W+1024;   ldw=1280; optr=pre_b + ((size_t)((i-1)&1)*3+2)*BB*HH;  ldo=HH; }
  int ar=tid>>2, ak=(tid&3)*8;
  int rt=tid>>4, ct=tid&15;
  float acc[4][4];
  #pragma unroll
  for (int j=0;j<4;j++){
    #pragma unroll
    for (int l=0;l<4;l++) acc[j][l]=0.f;
  }
  for (int ko=0;ko<256;ko+=32){
    const float* asrc = aptr + (size_t)(m0+ar)*lda + ko + ak;
    float4 a0=*(const float4*)asrc, a1=*(const float4*)(asrc+4);
    const float* wsrc = wptr + (size_t)(n0+ar)*ldw + ko + ak;
    float4 w0=*(const float4*)wsrc, w1=*(const float4*)(wsrc+4);
    __syncthreads();
    As[ak+0][ar]=a0.x; As[ak+1][ar]=a0.y; As[ak+2][ar]=a0.z; As[ak+3][ar]=a0.w;
    As[ak+4][ar]=a1.x; As[ak+5][ar]=a1.y; As[ak+6][ar]=a1.z; As[ak+7][ar]=a1.w;
    Ws[ak+0][ar]=w0.x; Ws[ak+1][ar]=w0.y; Ws[ak+2][ar]=w0.z; Ws[ak+3][ar]=w0.w;
    Ws[ak+4][ar]=w1.x; Ws[ak+5][ar]=w1.y; Ws[ak+6][ar]=w1.z; Ws[ak+7][ar]=w1.w;
    __syncthreads();
    #pragma unroll
    for (int kk=0;kk<32;kk++){
      float4 a=*(const float4*)&As[kk][rt*4];
      float4 w=*(const float4*)&Ws[kk][ct*4];
      float a4[4]={a.x,a.y,a.z,a.w};
      float w4[4]={w.x,w.y,w.z,w.w};
      #pragma unroll
      for (int j=0;j<4;j++){
        #pragma unroll
        for (int l=0;l<4;l++) acc[j][l]+=a4[j]*w4[l];
      }
    }
  }
  #pragma unroll
  for (int j=0;j<4;j++){
    float4 ov; ov.x=acc[j][0]; ov.y=acc[j][1]; ov.z=acc[j][2]; ov.w=acc[j][3];
    *(float4*)&optr[(size_t)(m0+rt*4+j)*ldo + n0 + ct*4] = ov;
  }
}

__global__ __launch_bounds__(256) void k_loss(const float* __restrict__ nll, float* __restrict__ out)
{
  __shared__ float sm[256];
  int tid=threadIdx.x;
  float s=0.f;
  for (int idx=tid; idx<TM1*BB; idx+=256) s += nll[idx];
  sm[tid]=s; __syncthreads();
  for (int off=128; off; off>>=1){
    if (tid<off) sm[tid]+=sm[tid+off];
    __syncthreads();
  }
  if (tid==0) out[0]=sm[0];
}

extern "C" void kernel_launch(void* const* d_in, const int* in_sizes, int n_in,
                              void* d_out, int out_size, void* d_ws, size_t ws_size,
                              hipStream_t stream)
{
  const int*   input    = (const int*)  d_in[0];
  const float* src_emb  = (const float*)d_in[1];
  const float* trg_emb  = (const float*)d_in[2];
  const float* eWih_f   = (const float*)d_in[3];
  const float* eWhh_f   = (const float*)d_in[4];
  const float* ebih_f   = (const float*)d_in[5];
  const float* ebhh_f   = (const float*)d_in[6];
  const float* eWih_b   = (const float*)d_in[7];
  const float* eWhh_b   = (const float*)d_in[8];
  const float* ebih_b   = (const float*)d_in[9];
  const float* ebhh_b   = (const float*)d_in[10];
  const float* bridge_W = (const float*)d_in[11];
  const float* bridge_b = (const float*)d_in[12];
  const float* attn_Wk  = (const float*)d_in[13];
  const float* attn_Wq  = (const float*)d_in[14];
  const float* attn_We  = (const float*)d_in[15];
  const float* dec_Wih  = (const float*)d_in[16];
  const float* dec_Whh  = (const float*)d_in[17];
  const float* dec_bih  = (const float*)d_in[18];
  const float* dec_bhh  = (const float*)d_in[19];
  const float* pre_W    = (const float*)d_in[20];
  const float* gen_W    = (const float*)d_in[21];

  float* F = (float*)d_ws;
  size_t o=0;
  float* tab_gi_f = F+o; o+=(size_t)VV*H3;
  float* tab_gi_b = F+o; o+=(size_t)VV*H3;
  float* tab_dec  = F+o; o+=(size_t)VV*H3;
  float* tab_pre  = F+o; o+=(size_t)VV*HH;
  float* h_f      = F+o; o+=(size_t)2*BB*HH;
  float* h_b      = F+o; o+=(size_t)2*BB*HH;
  float* gh_enc   = F+o; o+=(size_t)2*BB*1536;
  float* hd       = F+o; o+=(size_t)2*BB*HH;
  float* qb       = F+o; o+=(size_t)BB*HH;
  float* ctxb     = F+o; o+=(size_t)2*BB*H2;
  float* gh_dec   = F+o; o+=(size_t)2*BB*H3;
  float* gi_dec   = F+o; o+=(size_t)4*BB*H3;
  float* pre_b    = F+o; o+=(size_t)6*BB*HH;
  float* nll      = F+o; o+=(size_t)TM1*BB;
  u16* enc_out = (u16*)(F+o);
  u16* pk = enc_out + (size_t)BB*TT*H2;

  dim3 blk(256,1,1);
  k_tables<<<dim3(VV,10),blk,0,stream>>>(src_emb,trg_emb,eWih_f,ebih_f,eWih_b,ebih_b,
                                         dec_Wih,dec_bih,pre_W,
                                         tab_gi_f,tab_gi_b,tab_dec,tab_pre);
  for (int s=0;s<TT;s++)
    k_enc_step<<<dim3(24,8),blk,0,stream>>>(s,input,eWhh_f,eWhh_b,ebhh_f,ebhh_b,
                                            tab_gi_f,tab_gi_b,h_f,h_b,gh_enc,enc_out);
  k_enc_final<<<dim3(2,8),blk,0,stream>>>(input,ebhh_f,ebhh_b,tab_gi_f,tab_gi_b,
                                          h_f,h_b,gh_enc,enc_out);
  k_pk<<<dim3(4,1024),blk,0,stream>>>(enc_out,attn_Wk,pk);
  k_bridge<<<dim3(4,8),blk,0,stream>>>(h_f,h_b,bridge_W,bridge_b,hd);

  for (int i=0;i<TM1;i++){
    k_dec_g<<<dim3(8,16),blk,0,stream>>>(i,1,input,attn_Wq,tab_dec,dec_bhh,gh_dec,gi_dec,hd,qb);
    k_dec_attn<<<dim3(BB),blk,0,stream>>>(i,1,input,qb,pk,enc_out,attn_We,gen_W,tab_pre,pre_b,ctxb,nll);
    k_dec_gemm<<<dim3(i?48:36,8),blk,0,stream>>>(i,0,hd,ctxb,dec_Whh,dec_Wih,pre_W,gh_dec,gi_dec,pre_b);
  }
  // tails: h^(127) (gates only), nll_125, pre_126, nll_126
  k_dec_g<<<dim3(1,16),blk,0,stream>>>(TM1,0,input,attn_Wq,tab_dec,dec_bhh,gh_dec,gi_dec,hd,qb);
  k_dec_attn<<<dim3(BB),blk,0,stream>>>(TM1,0,input,qb,pk,enc_out,attn_We,gen_W,tab_pre,pre_b,ctxb,nll);
  k_dec_gemm<<<dim3(12,8),blk,0,stream>>>(TM1,36,hd,ctxb,dec_Whh,dec_Wih,pre_W,gh_dec,gi_dec,pre_b);
  k_dec_attn<<<dim3(BB),blk,0,stream>>>(TT,0,input,qb,pk,enc_out,attn_We,gen_W,tab_pre,pre_b,ctxb,nll);
  k_loss<<<dim3(1),blk,0,stream>>>(nll,(float*)d_out);
}

// Round 2
// 14863.205 us; speedup vs baseline: 1.2358x; 1.2358x over previous
//
#include <hip/hip_runtime.h>

#define BB 512
#define TT 128
#define EE 512
#define HH 256
#define VV 39
#define H3 768
#define H2 512
#define TM1 127
#define NEGF (-3.402823466e38f)

typedef unsigned short u16;
typedef unsigned int u32;
typedef __attribute__((ext_vector_type(8))) short s16x8;
typedef __attribute__((ext_vector_type(4))) float f32x4;

__device__ __forceinline__ float b2f(u16 u){ u32 x=((u32)u)<<16; return __uint_as_float(x); }
__device__ __forceinline__ u16 f2b(float f){ u32 x=__float_as_uint(f); u32 r=(x+0x7fffu+((x>>16)&1u))>>16; return (u16)r; }
__device__ __forceinline__ float sigm(float x){ return 1.f/(1.f+__expf(-x)); }
__device__ __forceinline__ float tanh1(float x){ float t=__expf(2.f*x); return 1.f-2.f/(t+1.f); }

// ---------------------------------------------------------------------------
// Per-token input-projection tables (V=39):
// tab_gi_f/b[v][n] = src_emb[v].Wih[n] + bih[n]; tab_dec likewise (emb part of
// dec_Wih, +dec_bih); tab_pre[v][n] = trg_emb[v].pre_W[n][0:512].
__global__ __launch_bounds__(256) void k_tables(
    const float* __restrict__ src_emb, const float* __restrict__ trg_emb,
    const float* __restrict__ Wih_f, const float* __restrict__ bih_f,
    const float* __restrict__ Wih_b, const float* __restrict__ bih_b,
    const float* __restrict__ dec_Wih, const float* __restrict__ dec_bih,
    const float* __restrict__ pre_W,
    float* __restrict__ tab_gi_f, float* __restrict__ tab_gi_b,
    float* __restrict__ tab_dec, float* __restrict__ tab_pre)
{
  int v = blockIdx.x;
  int y = blockIdx.y;
  int tid = threadIdx.x;
  if (y < 9){
    int seg = y/3, part = y%3;
    int n = part*256 + tid;
    const float* emb; const float* W; const float* bias; float* out; int ldw;
    if (seg==0){ emb=src_emb; W=Wih_f; bias=bih_f; out=tab_gi_f; ldw=EE; }
    else if (seg==1){ emb=src_emb; W=Wih_b; bias=bih_b; out=tab_gi_b; ldw=EE; }
    else { emb=trg_emb; W=dec_Wih; bias=dec_bih; out=tab_dec; ldw=EE+H2; }
    float acc = bias[n];
    const float* er = emb + (size_t)v*EE;
    const float* wr = W + (size_t)n*ldw;
    for (int k=0;k<EE;k++) acc += er[k]*wr[k];
    out[(size_t)v*H3 + n] = acc;
  } else {
    int n = tid;
    float acc = 0.f;
    const float* er = trg_emb + (size_t)v*EE;
    const float* wr = pre_W + (size_t)n*1280;
    for (int k=0;k<EE;k++) acc += er[k]*wr[k];
    tab_pre[(size_t)v*HH + n] = acc;
  }
}

// Generic fp32 -> bf16 weight convert: dst[r*cols+c] = src[r*ld + off + c]
__global__ __launch_bounds__(256) void k_cvt(const float* __restrict__ src,
    u16* __restrict__ dst, int rows, int cols, int ld, int off)
{
  int idx = blockIdx.x*256 + threadIdx.x;
  if (idx >= rows*cols) return;
  int r = idx/cols, c = idx - r*cols;
  dst[idx] = f2b(src[(size_t)r*ld + off + c]);
}

// ---------------------------------------------------------------------------
// Encoder step s (1..127), both dirs. Phase A: gates of step s-1 -> h_s (LDS
// bf16, once per m-tile-half). Phase B: gh_s = h_s @ Whh^T via MFMA.
// grid(32): bx = dir*16 + mtile*2 + colhalf. block 512 (8 waves).
__global__ __launch_bounds__(512) void k_enc_step(int s, const int* __restrict__ input,
    const u16* __restrict__ wb_f, const u16* __restrict__ wb_b,
    const float* __restrict__ bhh_f, const float* __restrict__ bhh_b,
    const float* __restrict__ tab_f, const float* __restrict__ tab_b,
    float* __restrict__ h_f, float* __restrict__ h_b,
    float* __restrict__ gh_enc, u16* __restrict__ enc_out)
{
  __shared__ u16 hs[64][264];   // h_s rows (row-major, K contig), +8 pad
  int bx = blockIdx.x;
  int dirb = bx>>4, rem = bx&15, mt = rem>>1, ch = rem&1;
  int m0 = mt*64;
  int tid = threadIdx.x;
  const float* tab = dirb ? tab_b : tab_f;
  const float* bhh = dirb ? bhh_b : bhh_f;
  float* hW = (dirb? h_b : h_f) + (size_t)(s&1)*BB*HH;
  const float* hR = (dirb? h_b : h_f) + (size_t)((s-1)&1)*BB*HH;
  const float* ghR = gh_enc + (size_t)((s-1)&1)*BB*1536 + dirb*H3;
  float* ghW = gh_enc + (size_t)(s&1)*BB*1536 + dirb*H3;
  int tcol = dirb ? (TT - s) : (s - 1);
  // Phase A: 512 threads, each col c for 32 rows
  {
    int c = tid & 255, rh = tid >> 8;
    float b_r=bhh[c], b_z=bhh[c+256], b_n=bhh[c+512];
    for (int r = rh*32; r < rh*32+32; r++){
      int b = m0 + r;
      int tok = input[b*TT + tcol];
      const float* tg = tab + (size_t)tok*H3;
      float g0,g1,g2,hp;
      if (s==1){ g0=0.f; g1=0.f; g2=0.f; hp=0.f; }
      else {
        const float* gr = ghR + (size_t)b*1536;
        g0=gr[c]; g1=gr[c+256]; g2=gr[c+512]; hp=hR[b*HH+c];
      }
      float rg = sigm(tg[c]     + g0 + b_r);
      float zg = sigm(tg[c+256] + g1 + b_z);
      float ng = tanh1(tg[c+512] + rg*(g2 + b_n));
      float hv = (1.f-zg)*ng + zg*hp;
      hs[r][c] = f2b(hv);
      if (ch==0){
        hW[b*HH+c] = hv;
        enc_out[((size_t)b*TT + tcol)*H2 + dirb*HH + c] = f2b(hv);
      }
    }
  }
  __syncthreads();
  // Phase B: 8 waves: 4 row-groups x 2 col-groups(192). 12 tiles/wave.
  int wv = tid>>6, lane = tid&63;
  int wr = (wv&3)*16, wc = (wv>>2)*192;
  int l15 = lane&15, kg = (lane>>4)*8;
  int nbase = ch*384 + wc;
  const u16* Wb = dirb? wb_b : wb_f;
  f32x4 acc[12];
  #pragma unroll
  for (int t=0;t<12;t++) acc[t] = (f32x4){0.f,0.f,0.f,0.f};
  const u16* arow = &hs[wr + l15][0];
  for (int ko=0; ko<256; ko+=32){
    s16x8 af = *(const s16x8*)(arow + ko + kg);
    #pragma unroll
    for (int nt=0; nt<12; nt++){
      s16x8 bf = *(const s16x8*)(Wb + (size_t)(nbase + nt*16 + l15)*HH + ko + kg);
      acc[nt] = __builtin_amdgcn_mfma_f32_16x16x32_bf16(af, bf, acc[nt], 0,0,0);
    }
  }
  int rb = m0 + wr + (lane>>4)*4;
  #pragma unroll
  for (int nt=0; nt<12; nt++){
    int col = nbase + nt*16 + l15;
    #pragma unroll
    for (int j=0;j<4;j++)
      ghW[(size_t)(rb+j)*1536 + col] = acc[nt][j];
  }
}

// Encoder tail (s=128): gates only, both dirs. grid (2,8), block 256.
__global__ __launch_bounds__(256) void k_enc_final(const int* __restrict__ input,
    const float* __restrict__ bhh_f, const float* __restrict__ bhh_b,
    const float* __restrict__ tab_f, const float* __restrict__ tab_b,
    float* __restrict__ h_f, float* __restrict__ h_b,
    const float* __restrict__ gh_enc, u16* __restrict__ enc_out)
{
  int dirb = blockIdx.x;
  int m0 = blockIdx.y*64;
  int c = threadIdx.x;
  const float* tab = dirb? tab_b : tab_f;
  const float* bhh = dirb? bhh_b : bhh_f;
  float* hW = (dirb? h_b : h_f);                         // parity 0 (s=128)
  const float* hR = (dirb? h_b : h_f) + (size_t)BB*HH;   // parity 1
  const float* ghR = gh_enc + (size_t)BB*1536 + dirb*H3; // parity 1
  int tcol = dirb ? 0 : 127;
  float b_r=bhh[c], b_z=bhh[c+256], b_n=bhh[c+512];
  for (int r=0;r<64;r++){
    int b=m0+r;
    int tok=input[b*TT+tcol];
    const float* tg = tab + (size_t)tok*H3;
    const float* gr = ghR + (size_t)b*1536;
    float rg=sigm(tg[c]+gr[c]+b_r);
    float zg=sigm(tg[c+256]+gr[c+256]+b_z);
    float ng=tanh1(tg[c+512]+rg*(gr[c+512]+b_n));
    float hv=(1.f-zg)*ng+zg*hR[b*HH+c];
    hW[b*HH+c]=hv;
    enc_out[((size_t)b*TT+tcol)*H2 + dirb*HH + c]=f2b(hv);
  }
}

// proj_key = enc_out @ Wk^T : M=65536, N=256, K=512, MFMA. grid(1024), block 256.
__global__ __launch_bounds__(256) void k_pk(const u16* __restrict__ enc_out,
    const u16* __restrict__ wbk, u16* __restrict__ pk)
{
  int m0 = blockIdx.x*64;
  int tid = threadIdx.x, wv = tid>>6, lane = tid&63;
  int l15 = lane&15, kg = (lane>>4)*8;
  int n0 = wv*64;
  f32x4 acc[4][4];
  #pragma unroll
  for (int rt=0;rt<4;rt++)
    #pragma unroll
    for (int nt=0;nt<4;nt++) acc[rt][nt] = (f32x4){0.f,0.f,0.f,0.f};
  for (int ko=0; ko<512; ko+=32){
    s16x8 a[4], b[4];
    #pragma unroll
    for (int rt=0;rt<4;rt++) a[rt] = *(const s16x8*)(enc_out + (size_t)(m0+rt*16+l15)*H2 + ko + kg);
    #pragma unroll
    for (int nt=0;nt<4;nt++) b[nt] = *(const s16x8*)(wbk + (size_t)(n0+nt*16+l15)*H2 + ko + kg);
    #pragma unroll
    for (int rt=0;rt<4;rt++)
      #pragma unroll
      for (int nt=0;nt<4;nt++)
        acc[rt][nt] = __builtin_amdgcn_mfma_f32_16x16x32_bf16(a[rt], b[nt], acc[rt][nt], 0,0,0);
  }
  #pragma unroll
  for (int rt=0;rt<4;rt++){
    int rbase = m0 + rt*16 + (lane>>4)*4;
    #pragma unroll
    for (int nt=0;nt<4;nt++){
      int col = n0 + nt*16 + l15;
      #pragma unroll
      for (int j=0;j<4;j++)
        pk[(size_t)(rbase+j)*HH + col] = f2b(acc[rt][nt][j]);
    }
  }
}

// hidden = tanh([h_f|h_b] @ bridge_W^T + b). fp32 (one-time). grid (4,8).
__global__ __launch_bounds__(256) void k_bridge(const float* __restrict__ h_f,
    const float* __restrict__ h_b, const float* __restrict__ bw,
    const float* __restrict__ bb, float* __restrict__ hd)
{
  __shared__ float As[32][68];
  __shared__ float Ws[32][68];
  int n0=blockIdx.x*64, m0=blockIdx.y*64, tid=threadIdx.x;
  int ar=tid>>2, ak=(tid&3)*8;
  int rt=tid>>4, ct=tid&15;
  float acc[4][4];
  #pragma unroll
  for (int j=0;j<4;j++){
    #pragma unroll
    for (int l=0;l<4;l++) acc[j][l]=0.f;
  }
  for (int ko=0;ko<512;ko+=32){
    int k0=ko+ak;
    const float* asrc = (k0<256)? (h_f + (size_t)(m0+ar)*HH + k0)
                                : (h_b + (size_t)(m0+ar)*HH + (k0-256));
    float4 a0=*(const float4*)asrc, a1=*(const float4*)(asrc+4);
    const float* wsrc = bw + (size_t)(n0+ar)*H2 + k0;
    float4 w0=*(const float4*)wsrc, w1=*(const float4*)(wsrc+4);
    __syncthreads();
    As[ak+0][ar]=a0.x; As[ak+1][ar]=a0.y; As[ak+2][ar]=a0.z; As[ak+3][ar]=a0.w;
    As[ak+4][ar]=a1.x; As[ak+5][ar]=a1.y; As[ak+6][ar]=a1.z; As[ak+7][ar]=a1.w;
    Ws[ak+0][ar]=w0.x; Ws[ak+1][ar]=w0.y; Ws[ak+2][ar]=w0.z; Ws[ak+3][ar]=w0.w;
    Ws[ak+4][ar]=w1.x; Ws[ak+5][ar]=w1.y; Ws[ak+6][ar]=w1.z; Ws[ak+7][ar]=w1.w;
    __syncthreads();
    #pragma unroll
    for (int kk=0;kk<32;kk++){
      float4 a=*(const float4*)&As[kk][rt*4];
      float4 w=*(const float4*)&Ws[kk][ct*4];
      float a4[4]={a.x,a.y,a.z,a.w};
      float w4[4]={w.x,w.y,w.z,w.w};
      #pragma unroll
      for (int j=0;j<4;j++){
        #pragma unroll
        for (int l=0;l<4;l++) acc[j][l]+=a4[j]*w4[l];
      }
    }
  }
  #pragma unroll
  for (int j=0;j<4;j++){
    int row=m0+rt*4+j;
    #pragma unroll
    for (int l=0;l<4;l++){
      int col=n0+ct*4+l;
      hd[(size_t)row*HH+col]=tanh1(acc[j][l]+bb[col]);
    }
  }
}

// Decoder gates (h_i from step i-1 state) + q_i = h_i @ Wq^T (MFMA).
// grid(32): 16 rows/block. block 256.
__global__ __launch_bounds__(256) void k_dec_g(int i, int do_q, const int* __restrict__ input,
    const u16* __restrict__ wbq, const float* __restrict__ tab_dec,
    const float* __restrict__ bhh, const float* __restrict__ gh_dec,
    const float* __restrict__ gi_dec, float* __restrict__ hd, u16* __restrict__ hd_bf,
    float* __restrict__ q)
{
  __shared__ u16 hs[16][264];
  int m0 = blockIdx.x*16;
  int tid = threadIdx.x;
  int c = tid;
  float* hdW = hd + (size_t)(i&1)*BB*HH;
  if (i == 0){
    for (int r=0;r<16;r++){
      float hv = hd[(size_t)(m0+r)*HH + c];    // bridge output, parity 0
      u16 hb = f2b(hv);
      hs[r][c] = hb;
      hd_bf[(size_t)(m0+r)*HH + c] = hb;
    }
  } else {
    int p = (i-1)&1;
    const float* ghR = gh_dec + (size_t)p*BB*H3;
    const float* giR = gi_dec + (size_t)p*BB*H3;
    const float* hR  = hd + (size_t)p*BB*HH;
    float b_r=bhh[c], b_z=bhh[c+256], b_n=bhh[c+512];
    for (int r=0;r<16;r++){
      int b = m0+r;
      int tok = input[b*TT + (i-1)];
      const float* tg = tab_dec + (size_t)tok*H3;
      const float* gr = ghR + (size_t)b*H3;
      const float* gi = giR + (size_t)b*H3;
      float rg = sigm(tg[c]     + gi[c]     + gr[c]     + b_r);
      float zg = sigm(tg[c+256] + gi[c+256] + gr[c+256] + b_z);
      float ng = tanh1(tg[c+512] + gi[c+512] + rg*(gr[c+512] + b_n));
      float hv = (1.f-zg)*ng + zg*hR[b*HH + c];
      u16 hb = f2b(hv);
      hs[r][c] = hb;
      hdW[b*HH + c] = hv;
      hd_bf[b*HH + c] = hb;
    }
  }
  __syncthreads();
  if (!do_q) return;
  int wv=tid>>6, lane=tid&63, l15=lane&15, kg=(lane>>4)*8;
  int n0 = wv*64;
  f32x4 acc[4];
  #pragma unroll
  for (int nt=0;nt<4;nt++) acc[nt]=(f32x4){0.f,0.f,0.f,0.f};
  const u16* arow = &hs[l15][0];
  for (int ko=0;ko<256;ko+=32){
    s16x8 af = *(const s16x8*)(arow + ko + kg);
    #pragma unroll
    for (int nt=0;nt<4;nt++){
      s16x8 bf = *(const s16x8*)(wbq + (size_t)(n0+nt*16+l15)*HH + ko + kg);
      acc[nt] = __builtin_amdgcn_mfma_f32_16x16x32_bf16(af, bf, acc[nt], 0,0,0);
    }
  }
  int rb = m0 + (lane>>4)*4;
  #pragma unroll
  for (int nt=0;nt<4;nt++){
    int col = n0 + nt*16 + l15;
    #pragma unroll
    for (int j=0;j<4;j++)
      q[(size_t)(rb+j)*HH + col] = acc[nt][j];
  }
}

// Attention for step i (+ nll for step i-2). One block per batch row. grid(512).
__global__ __launch_bounds__(256) void k_dec_attn(int i, int do_attn, const int* __restrict__ input,
    const float* __restrict__ q, const u16* __restrict__ pk, const u16* __restrict__ enc_out,
    const float* __restrict__ We, const float* __restrict__ genW,
    const float* __restrict__ tab_pre, const float* __restrict__ pre_b,
    u16* __restrict__ ctx_bf, float* __restrict__ nll)
{
  __shared__ float se[128];
  __shared__ float sa[128];
  __shared__ float spre[256];
  __shared__ int   stok[128];
  __shared__ float redm[4];
  __shared__ float reds[4];
  int b = blockIdx.x;
  int tid = threadIdx.x;
  int lane = tid & 63;
  int w = tid >> 6;
  int do_nll = (i >= 2);
  if (do_attn && tid < 128) stok[tid] = input[b*TT + tid];
  if (do_nll){
    int tokp = input[b*TT + (i-2)];
    const float* pp = pre_b + (size_t)(i&1)*BB*HH;  // parity (i-2)&1 == i&1
    spre[tid] = tab_pre[(size_t)tokp*HH + tid] + pp[(size_t)b*HH + tid];
  }
  __syncthreads();
  if (do_nll && w==0){
    float lg = NEGF;
    if (lane < VV){
      float s=0.f;
      const float* gw = genW + (size_t)lane*HH;
      for (int d=0; d<HH; d++) s += spre[d]*gw[d];
      lg = s;
    }
    float m = lg;
    #pragma unroll
    for (int off=32; off; off>>=1) m = fmaxf(m, __shfl_xor(m, off));
    float pe = (lane<VV)? __expf(lg - m) : 0.f;
    float ssum = pe;
    #pragma unroll
    for (int off=32; off; off>>=1) ssum += __shfl_xor(ssum, off);
    int ty = input[b*TT + (i-1)];
    float lty = __shfl(lg, ty);
    if (lane==0){
      float val = (ty != 0) ? (m + __logf(ssum) - lty) : 0.f;
      nll[(size_t)(i-2)*BB + b] = val;
    }
  }
  if (do_attn){
    float4 qv = *(const float4*)(q + (size_t)b*HH + lane*4);
    float4 wv = *(const float4*)(We + lane*4);
    const u16* pkb = pk + (size_t)b*TT*HH;
    for (int it=0; it<32; it++){
      int t = w*32 + it;
      ushort4 kv = *(const ushort4*)(pkb + (size_t)t*HH + lane*4);
      float s = tanh1(qv.x + b2f(kv.x))*wv.x + tanh1(qv.y + b2f(kv.y))*wv.y
              + tanh1(qv.z + b2f(kv.z))*wv.z + tanh1(qv.w + b2f(kv.w))*wv.w;
      #pragma unroll
      for (int off=32; off; off>>=1) s += __shfl_xor(s, off);
      if (lane==0) se[t] = (stok[t] != 0) ? s : NEGF;
    }
    __syncthreads();
    float v = (tid<128)? se[tid] : NEGF;
    float mm = v;
    #pragma unroll
    for (int off=32; off; off>>=1) mm = fmaxf(mm, __shfl_xor(mm, off));
    if (lane==0) redm[w]=mm;
    __syncthreads();
    float M = fmaxf(fmaxf(redm[0],redm[1]), fmaxf(redm[2],redm[3]));
    float pv = (tid<128)? __expf(v - M) : 0.f;
    float ps = pv;
    #pragma unroll
    for (int off=32; off; off>>=1) ps += __shfl_xor(ps, off);
    if (lane==0) reds[w]=ps;
    __syncthreads();
    float S = reds[0]+reds[1]+reds[2]+reds[3];
    if (tid<128) sa[tid] = pv/S;
    __syncthreads();
    const u16* eb = enc_out + (size_t)b*TT*H2;
    float c0=0.f, c1=0.f;
    for (int t=0;t<TT;t++){
      float a = sa[t];
      c0 += a*b2f(eb[(size_t)t*H2 + tid]);
      c1 += a*b2f(eb[(size_t)t*H2 + 256 + tid]);
    }
    u16* cb = ctx_bf + (size_t)(i&1)*BB*H2 + (size_t)b*H2;
    cb[tid] = f2b(c0);
    cb[tid+256] = f2b(c1);
  }
}

// Decoder MFMA GEMMs: x<12: gh_i (K=256); 12<=x<24: gi_i (K=512, ctx);
// 24<=x<28: pre_{i-1} (K=768: [h_i | ctx_{i-1}]). grid (nx,8), block 256.
__global__ __launch_bounds__(256) void k_dec_gemm(int i, int xoff,
    const u16* __restrict__ hd_bf, const u16* __restrict__ ctx_bf,
    const u16* __restrict__ wb_dhh, const u16* __restrict__ wb_dih,
    const u16* __restrict__ wb_pre,
    float* __restrict__ gh_dec, float* __restrict__ gi_dec, float* __restrict__ pre_b)
{
  int x = blockIdx.x + xoff;
  int m0 = blockIdx.y*64;
  int tid=threadIdx.x, wv=tid>>6, lane=tid&63;
  int l15=lane&15, kg=(lane>>4)*8;
  int mrow = m0 + wv*16;
  const u16* ctxC = ctx_bf + (size_t)(i&1)*BB*H2;
  const u16* ctxP = ctx_bf + (size_t)((i-1)&1)*BB*H2;
  const u16* aBase; int lda; const u16* wBase; int ldw; int K; int n0;
  float* optr; int ldo; int pre = 0;
  if (x < 12){       aBase=hd_bf; lda=HH; wBase=wb_dhh; ldw=HH; K=256; n0=x*64;
                     optr=gh_dec + (size_t)(i&1)*BB*H3; ldo=H3; }
  else if (x < 24){  aBase=ctxC;  lda=H2; wBase=wb_dih; ldw=H2; K=512; n0=(x-12)*64;
                     optr=gi_dec + (size_t)(i&1)*BB*H3; ldo=H3; }
  else {             aBase=hd_bf; lda=HH; wBase=wb_pre; ldw=H3; K=768; n0=(x-24)*64;
                     optr=pre_b + (size_t)((i-1)&1)*BB*HH; ldo=HH; pre=1; }
  f32x4 acc[4];
  #pragma unroll
  for (int nt=0;nt<4;nt++) acc[nt]=(f32x4){0.f,0.f,0.f,0.f};
  for (int ko=0; ko<K; ko+=32){
    const u16* ap;
    if (pre)
      ap = (ko<256) ? (hd_bf + (size_t)(mrow+l15)*HH + ko)
                    : (ctxP + (size_t)(mrow+l15)*H2 + (ko-256));
    else
      ap = aBase + (size_t)(mrow+l15)*lda + ko;
    s16x8 af = *(const s16x8*)(ap + kg);
    #pragma unroll
    for (int nt=0;nt<4;nt++){
      s16x8 bf = *(const s16x8*)(wBase + (size_t)(n0+nt*16+l15)*ldw + ko + kg);
      acc[nt] = __builtin_amdgcn_mfma_f32_16x16x32_bf16(af, bf, acc[nt], 0,0,0);
    }
  }
  int rb = mrow + (lane>>4)*4;
  #pragma unroll
  for (int nt=0;nt<4;nt++){
    int col = n0 + nt*16 + l15;
    #pragma unroll
    for (int j=0;j<4;j++)
      optr[(size_t)(rb+j)*ldo + col] = acc[nt][j];
  }
}

__global__ __launch_bounds__(256) void k_loss(const float* __restrict__ nll, float* __restrict__ out)
{
  __shared__ float sm[256];
  int tid=threadIdx.x;
  float s=0.f;
  for (int idx=tid; idx<TM1*BB; idx+=256) s += nll[idx];
  sm[tid]=s; __syncthreads();
  for (int off=128; off; off>>=1){
    if (tid<off) sm[tid]+=sm[tid+off];
    __syncthreads();
  }
  if (tid==0) out[0]=sm[0];
}

extern "C" void kernel_launch(void* const* d_in, const int* in_sizes, int n_in,
                              void* d_out, int out_size, void* d_ws, size_t ws_size,
                              hipStream_t stream)
{
  const int*   input    = (const int*)  d_in[0];
  const float* src_emb  = (const float*)d_in[1];
  const float* trg_emb  = (const float*)d_in[2];
  const float* eWih_f   = (const float*)d_in[3];
  const float* eWhh_f   = (const float*)d_in[4];
  const float* ebih_f   = (const float*)d_in[5];
  const float* ebhh_f   = (const float*)d_in[6];
  const float* eWih_b   = (const float*)d_in[7];
  const float* eWhh_b   = (const float*)d_in[8];
  const float* ebih_b   = (const float*)d_in[9];
  const float* ebhh_b   = (const float*)d_in[10];
  const float* bridge_W = (const float*)d_in[11];
  const float* bridge_b = (const float*)d_in[12];
  const float* attn_Wk  = (const float*)d_in[13];
  const float* attn_Wq  = (const float*)d_in[14];
  const float* attn_We  = (const float*)d_in[15];
  const float* dec_Wih  = (const float*)d_in[16];
  const float* dec_Whh  = (const float*)d_in[17];
  const float* dec_bih  = (const float*)d_in[18];
  const float* dec_bhh  = (const float*)d_in[19];
  const float* pre_W    = (const float*)d_in[20];
  const float* gen_W    = (const float*)d_in[21];

  float* F = (float*)d_ws;
  size_t o=0;
  float* tab_gi_f = F+o; o+=(size_t)VV*H3;
  float* tab_gi_b = F+o; o+=(size_t)VV*H3;
  float* tab_dec  = F+o; o+=(size_t)VV*H3;
  float* tab_pre  = F+o; o+=(size_t)VV*HH;
  float* h_f      = F+o; o+=(size_t)2*BB*HH;
  float* h_b      = F+o; o+=(size_t)2*BB*HH;
  float* gh_enc   = F+o; o+=(size_t)2*BB*1536;
  float* hd       = F+o; o+=(size_t)2*BB*HH;
  float* qb       = F+o; o+=(size_t)BB*HH;
  float* gh_dec   = F+o; o+=(size_t)2*BB*H3;
  float* gi_dec   = F+o; o+=(size_t)2*BB*H3;
  float* pre_b    = F+o; o+=(size_t)2*BB*HH;
  float* nll      = F+o; o+=(size_t)TM1*BB;
  u16* U = (u16*)(F+o);
  size_t uo=0;
  u16* enc_out = U+uo; uo+=(size_t)BB*TT*H2;
  u16* pk      = U+uo; uo+=(size_t)BB*TT*HH;
  u16* hd_bf   = U+uo; uo+=(size_t)BB*HH;
  u16* ctx_bf  = U+uo; uo+=(size_t)2*BB*H2;
  u16* wb_ehh_f= U+uo; uo+=(size_t)H3*HH;
  u16* wb_ehh_b= U+uo; uo+=(size_t)H3*HH;
  u16* wb_dhh  = U+uo; uo+=(size_t)H3*HH;
  u16* wb_dih  = U+uo; uo+=(size_t)H3*H2;
  u16* wb_pre  = U+uo; uo+=(size_t)HH*H3;
  u16* wb_wk   = U+uo; uo+=(size_t)HH*H2;
  u16* wb_wq   = U+uo; uo+=(size_t)HH*HH;

  dim3 blk(256,1,1);
  k_tables<<<dim3(VV,10),blk,0,stream>>>(src_emb,trg_emb,eWih_f,ebih_f,eWih_b,ebih_b,
                                         dec_Wih,dec_bih,pre_W,
                                         tab_gi_f,tab_gi_b,tab_dec,tab_pre);
  k_cvt<<<768,blk,0,stream>>>(eWhh_f, wb_ehh_f, 768,256,256,0);
  k_cvt<<<768,blk,0,stream>>>(eWhh_b, wb_ehh_b, 768,256,256,0);
  k_cvt<<<768,blk,0,stream>>>(dec_Whh, wb_dhh, 768,256,256,0);
  k_cvt<<<1536,blk,0,stream>>>(dec_Wih, wb_dih, 768,512,1024,512);
  k_cvt<<<768,blk,0,stream>>>(pre_W, wb_pre, 256,768,1280,512);
  k_cvt<<<512,blk,0,stream>>>(attn_Wk, wb_wk, 256,512,512,0);
  k_cvt<<<256,blk,0,stream>>>(attn_Wq, wb_wq, 256,256,256,0);

  for (int s=1;s<TT;s++)
    k_enc_step<<<dim3(32),dim3(512),0,stream>>>(s,input,wb_ehh_f,wb_ehh_b,ebhh_f,ebhh_b,
                                                tab_gi_f,tab_gi_b,h_f,h_b,gh_enc,enc_out);
  k_enc_final<<<dim3(2,8),blk,0,stream>>>(input,ebhh_f,ebhh_b,tab_gi_f,tab_gi_b,
                                          h_f,h_b,gh_enc,enc_out);
  k_pk<<<dim3(1024),blk,0,stream>>>(enc_out,wb_wk,pk);
  k_bridge<<<dim3(4,8),blk,0,stream>>>(h_f,h_b,bridge_W,bridge_b,hd);

  for (int i=0;i<TM1;i++){
    k_dec_g<<<dim3(32),blk,0,stream>>>(i,1,input,wb_wq,tab_dec,dec_bhh,gh_dec,gi_dec,hd,hd_bf,qb);
    k_dec_attn<<<dim3(BB),blk,0,stream>>>(i,1,input,qb,pk,enc_out,attn_We,gen_W,tab_pre,pre_b,ctx_bf,nll);
    k_dec_gemm<<<dim3(i?28:24,8),blk,0,stream>>>(i,0,hd_bf,ctx_bf,wb_dhh,wb_dih,wb_pre,gh_dec,gi_dec,pre_b);
  }
  // tails: h_127 (gates only), pre_126, nll_125, nll_126
  k_dec_g<<<dim3(32),blk,0,stream>>>(TM1,0,input,wb_wq,tab_dec,dec_bhh,gh_dec,gi_dec,hd,hd_bf,qb);
  k_dec_gemm<<<dim3(4,8),blk,0,stream>>>(TM1,24,hd_bf,ctx_bf,wb_dhh,wb_dih,wb_pre,gh_dec,gi_dec,pre_b);
  k_dec_attn<<<dim3(BB),blk,0,stream>>>(TM1,0,input,qb,pk,enc_out,attn_We,gen_W,tab_pre,pre_b,ctx_bf,nll);
  k_dec_attn<<<dim3(BB),blk,0,stream>>>(TT,0,input,qb,pk,enc_out,attn_We,gen_W,tab_pre,pre_b,ctx_bf,nll);
  k_loss<<<dim3(1),blk,0,stream>>>(nll,(float*)d_out);
}